// Round 1
// baseline (40926.193 us; speedup 1.0000x reference)
//
#include <hip/hip_runtime.h>
#include <hip/hip_bf16.h>
#include <hip/hip_cooperative_groups.h>

namespace cg = cooperative_groups;

typedef __attribute__((ext_vector_type(8))) short bf16x8;
typedef __attribute__((ext_vector_type(4))) float f32x4;

constexpr int NB = 64, NS = 512, ND = 512, NH = 1024;
constexpr int KTOT = ND + NH;          // 1536
constexpr int G4H = 4 * NH;            // 4096
constexpr int NWG = 256, NTHR = 512;
constexpr int KHALF = KTOT / 2;        // 768 per wave-pair half
constexpr int NKS = KHALF / 32;        // 24 MFMA k-steps per wave

__device__ inline unsigned short f2bf(float f) {
  union { float f; unsigned u; } v; v.f = f;
  unsigned r = v.u + 0x7FFFu + ((v.u >> 16) & 1u);  // RNE
  return (unsigned short)(r >> 16);
}

__device__ inline float sigmoidf_fast(float x) {
  return 1.0f / (1.0f + __expf(-x));
}
// safe tanh: saturates to +-1, no inf/inf NaN
__device__ inline float tanhf_fast(float x) {
  float e = __expf(2.0f * x);
  return 1.0f - 2.0f / (e + 1.0f);
}

__global__ __launch_bounds__(NTHR, 2)
void lstm_kernel(const float* __restrict__ x,
                 const float* __restrict__ Wih,
                 const float* __restrict__ Whh,
                 const float* __restrict__ bias,
                 float* __restrict__ out,
                 unsigned short* __restrict__ xbf,
                 unsigned short* __restrict__ hbuf)  // 2 ping-pong buffers of NB*NH bf16
{
  const int tid  = threadIdx.x;
  const int wg   = blockIdx.x;
  const int wave = tid >> 6;
  const int lane = tid & 63;
  const int bb   = wg & 3;        // batch block (4 x 16 rows)
  const int hb   = wg >> 2;       // hidden block (64 x 16 cols)
  const int g    = wave & 3;      // gate: 0=i 1=f 2=g 3=o
  const int kh   = wave >> 2;     // K half: 0 -> [0,768), 1 -> [768,1536)

  __shared__ float part[8][256];   // per-wave partial 16x16 gate tiles
  __shared__ float c_state[256];   // persistent cell state for this (bb,hb) patch

  // ---------- init: x -> bf16, zero h ping-pong, zero c ----------
  {
    const int nthr = NWG * NTHR;
    const int idx = wg * NTHR + tid;
    const float4* x4 = (const float4*)x;
    ushort4* xo = (ushort4*)xbf;
    const int n4 = NB * NS * ND / 4;
    for (int i = idx; i < n4; i += nthr) {
      float4 v = x4[i];
      ushort4 o;
      o.x = f2bf(v.x); o.y = f2bf(v.y); o.z = f2bf(v.z); o.w = f2bf(v.w);
      xo[i] = o;
    }
    for (int i = idx; i < 2 * NB * NH; i += nthr) hbuf[i] = 0;
    if (tid < 256) c_state[tid] = 0.0f;
  }

  // ---------- gather this wave's W fragments into registers (one-time) ----------
  // B-frag layout for mfma_f32_16x16x32_bf16: lane holds col = lane&15,
  // k = kbase + (lane>>4)*8 + j (8 contiguous k per lane).
  const int col = (g << 10) + (hb << 4) + (lane & 15);  // column in 4H gate space
  const int kg0 = (lane >> 4) << 3;
  bf16x8 wfrag[NKS];
#pragma unroll
  for (int s = 0; s < NKS; ++s) {
    const int k0 = kh * KHALF + s * 32 + kg0;
#pragma unroll
    for (int j = 0; j < 8; ++j) {
      const int k = k0 + j;
      const float wv = (k < ND) ? Wih[(size_t)k * G4H + col]
                                : Whh[(size_t)(k - ND) * G4H + col];
      wfrag[s][j] = (short)f2bf(wv);
    }
  }

  cg::grid_group grid = cg::this_grid();
  grid.sync();  // x/h buffers ready everywhere

  const int arow = (bb << 4) + (lane & 15);  // A-frag row = batch row
  float* hs_out = out;                                  // (B,S,H)
  float* ht_out = out + (size_t)NB * NS * NH;           // (B,H)
  float* ct_out = ht_out + NB * NH;                     // (B,H)

  for (int t = 0; t < NS; ++t) {
    const unsigned short* hcur = hbuf + (t & 1) * (NB * NH);
    f32x4 acc = {0.f, 0.f, 0.f, 0.f};
#pragma unroll
    for (int s = 0; s < NKS; ++s) {
      const int k0 = kh * KHALF + s * 32 + kg0;
      // A-frag: row = lane&15 (abs batch row), 8 contiguous k
      const unsigned short* ap = (k0 < ND)
          ? (xbf + (size_t)arow * (NS * ND) + (size_t)t * ND + k0)
          : (hcur + arow * NH + (k0 - ND));
      bf16x8 af = *(const bf16x8*)ap;
      acc = __builtin_amdgcn_mfma_f32_16x16x32_bf16(af, wfrag[s], acc, 0, 0, 0);
    }
    // C/D layout: col = lane&15, row = (lane>>4)*4 + reg  [m89-verified]
    {
      const int r0 = (lane >> 4) << 2;
      const int cc = lane & 15;
#pragma unroll
      for (int j = 0; j < 4; ++j)
        part[wave][(r0 + j) * 16 + cc] = acc[j];
    }
    __syncthreads();
    if (tid < 256) {
      const int cc = tid & 15;
      const int r  = tid >> 4;
      float pre[4];
#pragma unroll
      for (int gg = 0; gg < 4; ++gg)
        pre[gg] = part[gg][tid] + part[gg + 4][tid]
                + bias[(gg << 10) + (hb << 4) + cc];
      const float it = sigmoidf_fast(pre[0]);
      const float ft = sigmoidf_fast(pre[1]);
      const float gt = tanhf_fast(pre[2]);
      const float ot = sigmoidf_fast(pre[3]);
      const float cn = ft * c_state[tid] + it * gt;
      c_state[tid] = cn;
      const float hn = ot * tanhf_fast(cn);
      const int row  = (bb << 4) + r;
      const int hcol = (hb << 4) + cc;
      hs_out[(size_t)row * (NS * NH) + (size_t)t * NH + hcol] = hn;
      unsigned short* hnext = hbuf + ((t + 1) & 1) * (NB * NH);
      hnext[row * NH + hcol] = f2bf(hn);
      if (t == NS - 1) {
        ht_out[row * NH + hcol] = hn;
        ct_out[row * NH + hcol] = cn;
      }
    }
    __threadfence();   // release h writes device-wide (agent-scope wb/inv)
    grid.sync();       // everyone sees h(t+1); also protects part[] reuse
  }
}

extern "C" void kernel_launch(void* const* d_in, const int* in_sizes, int n_in,
                              void* d_out, int out_size, void* d_ws, size_t ws_size,
                              hipStream_t stream) {
  const float* x    = (const float*)d_in[0];
  const float* wih  = (const float*)d_in[1];
  const float* whh  = (const float*)d_in[2];
  const float* bias = (const float*)d_in[3];
  float* out = (float*)d_out;

  unsigned short* xbf  = (unsigned short*)d_ws;                      // NB*NS*ND bf16 = 32 MB
  unsigned short* hbuf = (unsigned short*)((char*)d_ws + (size_t)NB * NS * ND * 2);  // 2*NB*NH bf16

  void* args[] = { (void*)&x, (void*)&wih, (void*)&whh, (void*)&bias,
                   (void*)&out, (void*)&xbf, (void*)&hbuf };
  hipLaunchCooperativeKernel((const void*)lstm_kernel, dim3(NWG), dim3(NTHR),
                             args, 0, stream);
}

// Round 2
// 7118.834 us; speedup vs baseline: 5.7490x; 5.7490x over previous
//
#include <hip/hip_runtime.h>
#include <hip/hip_bf16.h>

typedef __attribute__((ext_vector_type(8))) short bf16x8;
typedef __attribute__((ext_vector_type(4))) float f32x4;

constexpr int NB = 64, NS = 512, ND = 512, NH = 1024;
constexpr int G4H = 4 * NH;            // 4096
constexpr int NWG = 256, NTHR = 512;
// Per-wave K split: wave kh (0/1) takes 8 x-k-steps + 16 h-k-steps (32 wide each)
constexpr int NXS = 8;                 // x k-steps per wave
constexpr int NHS = 16;                // h k-steps per wave
constexpr int NFR = NXS + NHS;         // 24 W fragments per wave

__device__ inline unsigned short f2bf(float f) {
  union { float f; unsigned u; } v; v.f = f;
  unsigned r = v.u + 0x7FFFu + ((v.u >> 16) & 1u);  // RNE
  return (unsigned short)(r >> 16);
}

__device__ inline float sigmoidf_fast(float x) {
  return 1.0f / (1.0f + __expf(-x));
}
__device__ inline float tanhf_fast(float x) {
  float e = __expf(2.0f * x);
  return 1.0f - 2.0f / (e + 1.0f);
}

// ---------------- prep: x -> bf16, zero h ping-pong + barrier counter ----------------
__global__ void prep_kernel(const float* __restrict__ x,
                            unsigned short* __restrict__ xbf,
                            unsigned short* __restrict__ hbuf,
                            unsigned int* __restrict__ cnt) {
  const int idx = blockIdx.x * blockDim.x + threadIdx.x;
  const int nthr = gridDim.x * blockDim.x;
  if (idx == 0) *cnt = 0u;
  const float4* x4 = (const float4*)x;
  ushort4* xo = (ushort4*)xbf;
  const int n4 = NB * NS * ND / 4;
  for (int i = idx; i < n4; i += nthr) {
    float4 v = x4[i];
    ushort4 o;
    o.x = f2bf(v.x); o.y = f2bf(v.y); o.z = f2bf(v.z); o.w = f2bf(v.w);
    xo[i] = o;
  }
  uint4* h4 = (uint4*)hbuf;
  const int nh4 = 2 * NB * NH * 2 / 16;
  for (int i = idx; i < nh4; i += nthr) h4[i] = uint4{0, 0, 0, 0};
}

// ---------------- main persistent kernel ----------------
__global__ __launch_bounds__(NTHR, 2)
void lstm_kernel(const float* __restrict__ Wih,
                 const float* __restrict__ Whh,
                 const float* __restrict__ bias,
                 const unsigned short* __restrict__ xbf,
                 unsigned short* __restrict__ hbuf,
                 unsigned int* __restrict__ cnt,
                 float* __restrict__ out)
{
  const int tid  = threadIdx.x;
  const int wg   = blockIdx.x;
  const int wave = tid >> 6;
  const int lane = tid & 63;
  const int bb   = wg & 3;        // batch block (4 x 16 rows)
  const int hb   = wg >> 2;       // hidden block (64 x 16 cols)
  const int g    = wave & 3;      // gate: 0=i 1=f 2=g 3=o
  const int kh   = wave >> 2;     // K-split half

  __shared__ float part[8][256];          // per-wave partial 16x16 gate tiles
  __shared__ float c_state[256];          // persistent cell state
  __shared__ unsigned short hstage[256];  // bf16 h staging for packed stores

  if (tid < 256) c_state[tid] = 0.0f;

  // ---------- one-time W fragment gather ----------
  // B-frag: lane holds col = lane&15, k = kbase + (lane>>4)*8 + j
  const int col = (g << 10) + (hb << 4) + (lane & 15);
  const int kg0 = (lane >> 4) << 3;
  bf16x8 wfrag[NFR];
#pragma unroll
  for (int f = 0; f < NXS; ++f) {          // x-part: k in [ (kh*8+f)*32 , +32 )
    const int k0 = (kh * NXS + f) * 32 + kg0;
#pragma unroll
    for (int j = 0; j < 8; ++j)
      wfrag[f][j] = (short)f2bf(Wih[(size_t)(k0 + j) * G4H + col]);
  }
#pragma unroll
  for (int i = 0; i < NHS; ++i) {          // h-part: k-512 in [ (kh*16+i)*32 , +32 )
    const int k0 = (kh * NHS + i) * 32 + kg0;
#pragma unroll
    for (int j = 0; j < 8; ++j)
      wfrag[NXS + i][j] = (short)f2bf(Whh[(size_t)(k0 + j) * G4H + col]);
  }

  const int arow = (bb << 4) + (lane & 15);   // batch row for A-frags
  float* hs_out = out;                                  // (B,S,H)
  float* ht_out = out + (size_t)NB * NS * NH;           // (B,H)
  float* ct_out = ht_out + NB * NH;                     // (B,H)

  const unsigned short* xrow = xbf + (size_t)arow * (NS * ND);

  __syncthreads();  // c_state ready

  for (int t = 0; t < NS; ++t) {
    const unsigned short* hcur = hbuf + (t & 1) * (NB * NH);

    // ---- issue h A-frag loads (coherent, LLC) ----
    bf16x8 hfrag[NHS];
#pragma unroll
    for (int i = 0; i < NHS; ++i) {
      const unsigned short* hp = hcur + arow * NH + (kh * NHS + i) * 32 + kg0;
      unsigned long long lo = __hip_atomic_load((const unsigned long long*)hp,
                                                __ATOMIC_RELAXED, __HIP_MEMORY_SCOPE_AGENT);
      unsigned long long hi = __hip_atomic_load((const unsigned long long*)(hp + 4),
                                                __ATOMIC_RELAXED, __HIP_MEMORY_SCOPE_AGENT);
      union { unsigned long long q[2]; bf16x8 v; } u;
      u.q[0] = lo; u.q[1] = hi;
      hfrag[i] = u.v;
    }

    f32x4 acc = {0.f, 0.f, 0.f, 0.f};
    // ---- x MFMAs (hide h-load latency) ----
    const unsigned short* xt = xrow + (size_t)t * ND;
#pragma unroll
    for (int f = 0; f < NXS; ++f) {
      bf16x8 af = *(const bf16x8*)(xt + (kh * NXS + f) * 32 + kg0);
      acc = __builtin_amdgcn_mfma_f32_16x16x32_bf16(af, wfrag[f], acc, 0, 0, 0);
    }
    // ---- h MFMAs ----
#pragma unroll
    for (int i = 0; i < NHS; ++i)
      acc = __builtin_amdgcn_mfma_f32_16x16x32_bf16(hfrag[i], wfrag[NXS + i], acc, 0, 0, 0);

    // C/D layout: col = lane&15, row = (lane>>4)*4 + reg
    {
      const int r0 = (lane >> 4) << 2;
      const int cc = lane & 15;
#pragma unroll
      for (int j = 0; j < 4; ++j)
        part[wave][(r0 + j) * 16 + cc] = acc[j];
    }
    __syncthreads();

    // ---- epilogue: 256 threads, one (row,col) each ----
    if (tid < 256) {
      const int cc = tid & 15;
      float pre[4];
#pragma unroll
      for (int gg = 0; gg < 4; ++gg)
        pre[gg] = part[gg][tid] + part[gg + 4][tid]
                + bias[(gg << 10) + (hb << 4) + cc];
      const float it = sigmoidf_fast(pre[0]);
      const float ft = sigmoidf_fast(pre[1]);
      const float gt = tanhf_fast(pre[2]);
      const float ot = sigmoidf_fast(pre[3]);
      const float cn = ft * c_state[tid] + it * gt;
      c_state[tid] = cn;
      const float hn = ot * tanhf_fast(cn);
      hstage[tid] = f2bf(hn);
      const int row  = (bb << 4) + (tid >> 4);
      const int hcol = (hb << 4) + cc;
      hs_out[(size_t)row * (NS * NH) + (size_t)t * NH + hcol] = hn;
      if (t == NS - 1) {
        ht_out[row * NH + hcol] = hn;
        ct_out[row * NH + hcol] = cn;
      }
    }
    __syncthreads();

    // ---- packed coherent h stores: 128 threads x u32 ----
    if (tid < 128) {
      const int r  = tid >> 3;          // 0..15
      const int c0 = (tid & 7) << 1;    // 0,2,..,14
      unsigned int v = (unsigned int)hstage[r * 16 + c0]
                     | ((unsigned int)hstage[r * 16 + c0 + 1] << 16);
      unsigned short* hnext = hbuf + ((t + 1) & 1) * (NB * NH);
      unsigned int* p = (unsigned int*)(hnext + (size_t)((bb << 4) + r) * NH + (hb << 4) + c0);
      __hip_atomic_store(p, v, __ATOMIC_RELAXED, __HIP_MEMORY_SCOPE_AGENT);
    }
    // drain this wave's coherent stores before anyone signals arrival
    asm volatile("s_waitcnt vmcnt(0)" ::: "memory");
    __syncthreads();

    // ---- lightweight grid barrier: monotonic counter in LLC ----
    if (tid == 0) {
      __hip_atomic_fetch_add(cnt, 1u, __ATOMIC_RELAXED, __HIP_MEMORY_SCOPE_AGENT);
      const unsigned int target = (unsigned int)NWG * (unsigned int)(t + 1);
      while (__hip_atomic_load(cnt, __ATOMIC_RELAXED, __HIP_MEMORY_SCOPE_AGENT) < target)
        __builtin_amdgcn_s_sleep(1);
    }
    __syncthreads();
  }
}

extern "C" void kernel_launch(void* const* d_in, const int* in_sizes, int n_in,
                              void* d_out, int out_size, void* d_ws, size_t ws_size,
                              hipStream_t stream) {
  const float* x    = (const float*)d_in[0];
  const float* wih  = (const float*)d_in[1];
  const float* whh  = (const float*)d_in[2];
  const float* bias = (const float*)d_in[3];
  float* out = (float*)d_out;

  // ws layout: [cnt 256B][hbuf 2*NB*NH bf16 = 256KB][xbf NB*NS*ND bf16 = 32MB]
  unsigned int*   cnt  = (unsigned int*)d_ws;
  unsigned short* hbuf = (unsigned short*)((char*)d_ws + 256);
  unsigned short* xbf  = (unsigned short*)((char*)d_ws + 256 + (size_t)2 * NB * NH * 2);

  prep_kernel<<<1024, 256, 0, stream>>>(x, xbf, hbuf, cnt);

  void* args[] = { (void*)&wih, (void*)&whh, (void*)&bias,
                   (void*)&xbf, (void*)&hbuf, (void*)&cnt, (void*)&out };
  hipLaunchCooperativeKernel((const void*)lstm_kernel, dim3(NWG), dim3(NTHR),
                             args, 0, stream);
}

// Round 3
// 5461.041 us; speedup vs baseline: 7.4942x; 1.3036x over previous
//
#include <hip/hip_runtime.h>
#include <hip/hip_bf16.h>

typedef __attribute__((ext_vector_type(8))) short bf16x8;
typedef __attribute__((ext_vector_type(4))) float f32x4;

constexpr int NB = 64, NS = 512, ND = 512, NH = 1024;
constexpr int G4H = 4 * NH;            // 4096
constexpr int NWG = 256, NTHR = 512;
constexpr int NXS = 8;                 // x k-steps per wave (8*32 = 256 of 512)
constexpr int NHS = 16;                // h k-steps per wave (16*32 = 512 of 1024)

__device__ inline unsigned short f2bf(float f) {
  union { float f; unsigned u; } v; v.f = f;
  unsigned r = v.u + 0x7FFFu + ((v.u >> 16) & 1u);  // RNE
  return (unsigned short)(r >> 16);
}
__device__ inline float sigmoidf_fast(float x) { return 1.0f / (1.0f + __expf(-x)); }
__device__ inline float tanhf_fast(float x) {
  float e = __expf(2.0f * x);
  return 1.0f - 2.0f / (e + 1.0f);
}

// ---------------- prep: x -> bf16, zero h ping-pong + flags ----------------
__global__ void prep_kernel(const float* __restrict__ x,
                            unsigned short* __restrict__ xbf,
                            unsigned short* __restrict__ hbuf,
                            unsigned int* __restrict__ flags) {
  const int idx = blockIdx.x * blockDim.x + threadIdx.x;
  const int nthr = gridDim.x * blockDim.x;
  for (int i = idx; i < NWG * 16; i += nthr) flags[i] = 0u;
  const float4* x4 = (const float4*)x;
  ushort4* xo = (ushort4*)xbf;
  const int n4 = NB * NS * ND / 4;
  for (int i = idx; i < n4; i += nthr) {
    float4 v = x4[i];
    ushort4 o;
    o.x = f2bf(v.x); o.y = f2bf(v.y); o.z = f2bf(v.z); o.w = f2bf(v.w);
    xo[i] = o;
  }
  uint4* h4 = (uint4*)hbuf;
  const int nh4 = 2 * NB * NH * 2 / 16;
  for (int i = idx; i < nh4; i += nthr) h4[i] = uint4{0, 0, 0, 0};
}

// ---------------- main persistent kernel ----------------
__global__ __launch_bounds__(NTHR, 2)
void lstm_kernel(const float* __restrict__ Wih,
                 const float* __restrict__ Whh,
                 const float* __restrict__ bias,
                 const unsigned short* __restrict__ xbf,
                 unsigned short* __restrict__ hbuf,
                 unsigned int* __restrict__ flags,
                 float* __restrict__ out)
{
  const int tid  = threadIdx.x;
  const int wg   = blockIdx.x;
  const int wave = tid >> 6;
  const int lane = tid & 63;
  const int bb   = wg & 3;        // batch block: barrier group
  const int hb   = wg >> 2;       // hidden block
  const int g    = wave & 3;      // gate
  const int kh   = wave >> 2;     // K-split half

  __shared__ float part[8][272];  // stride 17*16: kill 4-way bank conflict
  __shared__ float c_state[256];

  if (tid < 256) c_state[tid] = 0.0f;

  // ---------- one-time W fragment gather (B-frag: col=lane&15, k=kbase+(lane>>4)*8+j) ----
  const int col = (g << 10) + (hb << 4) + (lane & 15);
  const int kg0 = (lane >> 4) << 3;
  bf16x8 wfx[NXS], wfh[NHS];
#pragma unroll
  for (int f = 0; f < NXS; ++f) {
    const int k0 = (kh * NXS + f) * 32 + kg0;
#pragma unroll
    for (int j = 0; j < 8; ++j)
      wfx[f][j] = (short)f2bf(Wih[(size_t)(k0 + j) * G4H + col]);
  }
#pragma unroll
  for (int i = 0; i < NHS; ++i) {
    const int k0 = (kh * NHS + i) * 32 + kg0;
#pragma unroll
    for (int j = 0; j < 8; ++j)
      wfh[i][j] = (short)f2bf(Whh[(size_t)(k0 + j) * G4H + col]);
  }

  const int arow = (bb << 4) + (lane & 15);
  float* hs_out = out;                               // (B,S,H)
  float* ht_out = out + (size_t)NB * NS * NH;        // (B,H)
  float* ct_out = ht_out + NB * NH;                  // (B,H)
  const unsigned short* xrow = xbf + (size_t)arow * (NS * ND);

  // preload x A-frags for t=0
  bf16x8 xf[NXS];
#pragma unroll
  for (int f = 0; f < NXS; ++f)
    xf[f] = *(const bf16x8*)(xrow + (kh * NXS + f) * 32 + kg0);

  __syncthreads();

  for (int t = 0; t < NS; ++t) {
    const unsigned short* hcur = hbuf + (t & 1) * (NB * NH);

    // ---- coherent h A-frag loads (LLC) ----
    bf16x8 hf[NHS];
#pragma unroll
    for (int i = 0; i < NHS; ++i) {
      const unsigned short* hp = hcur + arow * NH + (kh * NHS + i) * 32 + kg0;
      unsigned long long lo = __hip_atomic_load((const unsigned long long*)hp,
                                                __ATOMIC_RELAXED, __HIP_MEMORY_SCOPE_AGENT);
      unsigned long long hi = __hip_atomic_load((const unsigned long long*)(hp + 4),
                                                __ATOMIC_RELAXED, __HIP_MEMORY_SCOPE_AGENT);
      union { unsigned long long q[2]; bf16x8 v; } u;
      u.q[0] = lo; u.q[1] = hi;
      hf[i] = u.v;
    }

    // ---- MFMA: 3 independent chains ----
    f32x4 a0 = {0.f,0.f,0.f,0.f}, a1 = {0.f,0.f,0.f,0.f}, a2 = {0.f,0.f,0.f,0.f};
#pragma unroll
    for (int f = 0; f < NXS; ++f)
      a0 = __builtin_amdgcn_mfma_f32_16x16x32_bf16(xf[f], wfx[f], a0, 0, 0, 0);
#pragma unroll
    for (int i = 0; i < 8; ++i)
      a1 = __builtin_amdgcn_mfma_f32_16x16x32_bf16(hf[i], wfh[i], a1, 0, 0, 0);
#pragma unroll
    for (int i = 8; i < 16; ++i)
      a2 = __builtin_amdgcn_mfma_f32_16x16x32_bf16(hf[i], wfh[i], a2, 0, 0, 0);
    f32x4 acc = (a0 + a1) + a2;

    // C/D layout: col = lane&15, row = (lane>>4)*4 + reg
    {
      const int r0 = (lane >> 4) << 2;
      const int cc = lane & 15;
#pragma unroll
      for (int j = 0; j < 4; ++j)
        part[wave][(r0 + j) * 17 + cc] = acc[j];
    }
    __syncthreads();  // #1

    // ---- x prefetch for t+1: retires under epilogue + barrier ----
    if (t + 1 < NS) {
      const unsigned short* xn = xrow + (size_t)(t + 1) * ND;
#pragma unroll
      for (int f = 0; f < NXS; ++f)
        xf[f] = *(const bf16x8*)(xn + (kh * NXS + f) * 32 + kg0);
    }

    // ---- epilogue: 256 threads (waves 0-3), one (row,col) each ----
    if (tid < 256) {
      const int cc = tid & 15;
      const int r  = tid >> 4;
      float pre[4];
#pragma unroll
      for (int gg = 0; gg < 4; ++gg)
        pre[gg] = part[gg][r * 17 + cc] + part[gg + 4][r * 17 + cc]
                + bias[(gg << 10) + (hb << 4) + cc];
      const float it = sigmoidf_fast(pre[0]);
      const float ft = sigmoidf_fast(pre[1]);
      const float gt = tanhf_fast(pre[2]);
      const float ot = sigmoidf_fast(pre[3]);
      const float cn = ft * c_state[tid] + it * gt;
      c_state[tid] = cn;
      const float hn = ot * tanhf_fast(cn);
      const int row  = (bb << 4) + r;
      const int hcol = (hb << 4) + cc;
      hs_out[(size_t)row * (NS * NH) + (size_t)t * NH + hcol] = hn;
      if (t == NS - 1) {
        ht_out[row * NH + hcol] = hn;
        ct_out[row * NH + hcol] = cn;
      }
      // pack bf16 pair via shfl; even lanes store one coherent u32
      unsigned int my = (unsigned int)f2bf(hn);
      unsigned int nb2 = (unsigned int)__shfl_xor((int)my, 1, 64);
      if ((tid & 1) == 0) {
        unsigned short* hnext = hbuf + ((t + 1) & 1) * (NB * NH);
        unsigned int* p = (unsigned int*)(hnext + (size_t)row * NH + hcol);
        __hip_atomic_store(p, my | (nb2 << 16), __ATOMIC_RELAXED, __HIP_MEMORY_SCOPE_AGENT);
      }
    }

    if (t < NS - 1) {
      // drain h stores (waves 0-3) before signaling
      if (wave < 4) asm volatile("s_waitcnt vmcnt(0)" ::: "memory");
      __syncthreads();  // #2: all WG stores drained

      // signal arrival: parallel flag store (own 64B line), by the polling wave
      if (tid == (7 << 6))
        __hip_atomic_store(flags + (size_t)wg * 16, (unsigned int)(t + 1),
                           __ATOMIC_RELAXED, __HIP_MEMORY_SCOPE_AGENT);
      // wave 7 polls the 64 flags of this bb-group (lane -> hb)
      if (wave == 7) {
        const unsigned int target = (unsigned int)(t + 1);
        const unsigned int* fp = flags + (size_t)((lane << 2) | bb) * 16;
        while (true) {
          unsigned int v = __hip_atomic_load(fp, __ATOMIC_RELAXED, __HIP_MEMORY_SCOPE_AGENT);
          if (__all((int)(v >= target))) break;
          __builtin_amdgcn_s_sleep(1);
        }
      }
      __syncthreads();  // #3: release all waves into step t+1
    }
  }
}

extern "C" void kernel_launch(void* const* d_in, const int* in_sizes, int n_in,
                              void* d_out, int out_size, void* d_ws, size_t ws_size,
                              hipStream_t stream) {
  const float* x    = (const float*)d_in[0];
  const float* wih  = (const float*)d_in[1];
  const float* whh  = (const float*)d_in[2];
  const float* bias = (const float*)d_in[3];
  float* out = (float*)d_out;

  // ws layout: [flags 16KB][hbuf 2*NB*NH bf16 = 256KB][xbf NB*NS*ND bf16 = 32MB]
  unsigned int*   flags = (unsigned int*)d_ws;
  unsigned short* hbuf  = (unsigned short*)((char*)d_ws + 16384);
  unsigned short* xbf   = (unsigned short*)((char*)d_ws + 16384 + (size_t)2 * NB * NH * 2);

  prep_kernel<<<1024, 256, 0, stream>>>(x, xbf, hbuf, flags);

  void* args[] = { (void*)&wih, (void*)&whh, (void*)&bias,
                   (void*)&xbf, (void*)&hbuf, (void*)&flags, (void*)&out };
  hipLaunchCooperativeKernel((const void*)lstm_kernel, dim3(NWG), dim3(NTHR),
                             args, 0, stream);
}

// Round 4
// 5387.304 us; speedup vs baseline: 7.5968x; 1.0137x over previous
//
#include <hip/hip_runtime.h>
#include <hip/hip_bf16.h>

typedef __attribute__((ext_vector_type(8))) short bf16x8;
typedef __attribute__((ext_vector_type(4))) float f32x4;

constexpr int NB = 64, NS = 512, ND = 512, NH = 1024;
constexpr int G4H = 4 * NH;            // 4096
constexpr int NWG = 256, NTHR = 512;
constexpr int NXS = 8;                 // x k-steps per wave (8*32 = 256 of 512)
constexpr int NHS = 16;                // h k-steps per wave (16*32 = 512 of 1024)
constexpr int PS  = 20;                // part[] row stride (floats): 2-way max

__device__ inline unsigned short f2bf(float f) {
  union { float f; unsigned u; } v; v.f = f;
  unsigned r = v.u + 0x7FFFu + ((v.u >> 16) & 1u);  // RNE
  return (unsigned short)(r >> 16);
}
__device__ inline float sigmoidf_fast(float x) { return 1.0f / (1.0f + __expf(-x)); }
__device__ inline float tanhf_fast(float x) {
  float e = __expf(2.0f * x);
  return 1.0f - 2.0f / (e + 1.0f);
}

// ---------------- prep: x -> bf16, zero h ping-pong + flags ----------------
__global__ void prep_kernel(const float* __restrict__ x,
                            unsigned short* __restrict__ xbf,
                            unsigned short* __restrict__ hbuf,
                            unsigned int* __restrict__ flags) {
  const int idx = blockIdx.x * blockDim.x + threadIdx.x;
  const int nthr = gridDim.x * blockDim.x;
  for (int i = idx; i < NWG * 16; i += nthr) flags[i] = 0u;
  const float4* x4 = (const float4*)x;
  ushort4* xo = (ushort4*)xbf;
  const int n4 = NB * NS * ND / 4;
  for (int i = idx; i < n4; i += nthr) {
    float4 v = x4[i];
    ushort4 o;
    o.x = f2bf(v.x); o.y = f2bf(v.y); o.z = f2bf(v.z); o.w = f2bf(v.w);
    xo[i] = o;
  }
  uint4* h4 = (uint4*)hbuf;
  const int nh4 = 2 * NB * NH * 2 / 16;
  for (int i = idx; i < nh4; i += nthr) h4[i] = uint4{0, 0, 0, 0};
}

// ---------------- main persistent kernel ----------------
// 1 WG/CU, 8 waves. waves_per_eu(2,2): RA targets exactly 2 waves/SIMD ->
// 256-VGPR cap, so all 32 coherent h-loads stay in flight (no serialization).
__global__ __launch_bounds__(NTHR) __attribute__((amdgpu_waves_per_eu(2, 2)))
void lstm_kernel(const float* __restrict__ Wih,
                 const float* __restrict__ Whh,
                 const float* __restrict__ bias,
                 const unsigned short* __restrict__ xbf,
                 unsigned short* __restrict__ hbuf,
                 unsigned int* __restrict__ flags,
                 float* __restrict__ out)
{
  const int tid  = threadIdx.x;
  const int wg   = blockIdx.x;
  const int wave = tid >> 6;
  const int lane = tid & 63;
  const int bb   = wg & 3;        // batch block: barrier group
  const int hb   = wg >> 2;       // hidden block
  const int g    = wave & 3;      // gate
  const int kh   = wave >> 2;     // K-split half

  __shared__ float part[8][16 * PS];
  __shared__ float c_state[256];

  if (tid < 256) c_state[tid] = 0.0f;

  // ---------- one-time W fragment gather (B-frag: col=lane&15, k=kbase+(lane>>4)*8+j) ----
  const int col = (g << 10) + (hb << 4) + (lane & 15);
  const int kg0 = (lane >> 4) << 3;
  bf16x8 wfx[NXS], wfh[NHS];
#pragma unroll
  for (int f = 0; f < NXS; ++f) {
    const int k0 = (kh * NXS + f) * 32 + kg0;
#pragma unroll
    for (int j = 0; j < 8; ++j)
      wfx[f][j] = (short)f2bf(Wih[(size_t)(k0 + j) * G4H + col]);
  }
#pragma unroll
  for (int i = 0; i < NHS; ++i) {
    const int k0 = (kh * NHS + i) * 32 + kg0;
#pragma unroll
    for (int j = 0; j < 8; ++j)
      wfh[i][j] = (short)f2bf(Whh[(size_t)(k0 + j) * G4H + col]);
  }

  const int arow = (bb << 4) + (lane & 15);
  float* hs_out = out;                               // (B,S,H)
  float* ht_out = out + (size_t)NB * NS * NH;        // (B,H)
  float* ct_out = ht_out + NB * NH;                  // (B,H)
  const unsigned short* xrow = xbf + (size_t)arow * (NS * ND);

  // preload x A-frags for t=0
  bf16x8 xf[NXS];
#pragma unroll
  for (int f = 0; f < NXS; ++f)
    xf[f] = *(const bf16x8*)(xrow + (kh * NXS + f) * 32 + kg0);

  __syncthreads();

  for (int t = 0; t < NS; ++t) {
    const unsigned short* hcur = hbuf + (t & 1) * (NB * NH);

    // ---- coherent h A-frag loads (LLC) — all 32 in flight ----
    bf16x8 hf[NHS];
#pragma unroll
    for (int i = 0; i < NHS; ++i) {
      const unsigned short* hp = hcur + arow * NH + (kh * NHS + i) * 32 + kg0;
      unsigned long long lo = __hip_atomic_load((const unsigned long long*)hp,
                                                __ATOMIC_RELAXED, __HIP_MEMORY_SCOPE_AGENT);
      unsigned long long hi = __hip_atomic_load((const unsigned long long*)(hp + 4),
                                                __ATOMIC_RELAXED, __HIP_MEMORY_SCOPE_AGENT);
      union { unsigned long long q[2]; bf16x8 v; } u;
      u.q[0] = lo; u.q[1] = hi;
      hf[i] = u.v;
    }

    // ---- MFMA: 3 independent chains ----
    f32x4 a0 = {0.f,0.f,0.f,0.f}, a1 = {0.f,0.f,0.f,0.f}, a2 = {0.f,0.f,0.f,0.f};
#pragma unroll
    for (int f = 0; f < NXS; ++f)
      a0 = __builtin_amdgcn_mfma_f32_16x16x32_bf16(xf[f], wfx[f], a0, 0, 0, 0);
#pragma unroll
    for (int i = 0; i < 8; ++i)
      a1 = __builtin_amdgcn_mfma_f32_16x16x32_bf16(hf[i], wfh[i], a1, 0, 0, 0);
#pragma unroll
    for (int i = 8; i < 16; ++i)
      a2 = __builtin_amdgcn_mfma_f32_16x16x32_bf16(hf[i], wfh[i], a2, 0, 0, 0);
    f32x4 acc = (a0 + a1) + a2;

    // C/D layout: col = lane&15, row = (lane>>4)*4 + reg
    {
      const int r0 = (lane >> 4) << 2;
      const int cc = lane & 15;
#pragma unroll
      for (int j = 0; j < 4; ++j)
        part[wave][(r0 + j) * PS + cc] = acc[j];
    }
    __syncthreads();  // #1

    // ---- epilogue: 256 threads (waves 0-3), one (row,col) each ----
    if (tid < 256) {
      const int cc = tid & 15;
      const int r  = tid >> 4;
      float pre[4];
#pragma unroll
      for (int gg = 0; gg < 4; ++gg)
        pre[gg] = part[gg][r * PS + cc] + part[gg + 4][r * PS + cc]
                + bias[(gg << 10) + (hb << 4) + cc];
      const float it = sigmoidf_fast(pre[0]);
      const float ft = sigmoidf_fast(pre[1]);
      const float gt = tanhf_fast(pre[2]);
      const float ot = sigmoidf_fast(pre[3]);
      const float cn = ft * c_state[tid] + it * gt;
      c_state[tid] = cn;
      const float hn = ot * tanhf_fast(cn);
      const int row  = (bb << 4) + r;
      const int hcol = (hb << 4) + cc;
      // coherent h store FIRST (on the critical path), then bulk output store
      unsigned int my = (unsigned int)f2bf(hn);
      unsigned int nb2 = (unsigned int)__shfl_xor((int)my, 1, 64);
      if ((tid & 1) == 0) {
        unsigned short* hnext = hbuf + ((t + 1) & 1) * (NB * NH);
        unsigned int* p = (unsigned int*)(hnext + (size_t)row * NH + hcol);
        __hip_atomic_store(p, my | (nb2 << 16), __ATOMIC_RELAXED, __HIP_MEMORY_SCOPE_AGENT);
      }
      hs_out[(size_t)row * (NS * NH) + (size_t)t * NH + hcol] = hn;
      if (t == NS - 1) {
        ht_out[row * NH + hcol] = hn;
        ct_out[row * NH + hcol] = cn;
      }
    }

    if (t < NS - 1) {
      // drain h stores (only waves 0-3 have outstanding stores)
      if (wave < 4) asm volatile("s_waitcnt vmcnt(0)" ::: "memory");
      __syncthreads();  // #2: all WG h stores globally visible (LLC)

      // x prefetch for t+1 — AFTER the drain, overlaps flag store + poll
      {
        const unsigned short* xn = xrow + (size_t)(t + 1) * ND;
#pragma unroll
        for (int f = 0; f < NXS; ++f)
          xf[f] = *(const bf16x8*)(xn + (kh * NXS + f) * 32 + kg0);
      }

      // signal arrival: parallel flag store (own 64B line), by the polling wave
      if (tid == (7 << 6))
        __hip_atomic_store(flags + (size_t)wg * 16, (unsigned int)(t + 1),
                           __ATOMIC_RELAXED, __HIP_MEMORY_SCOPE_AGENT);
      // wave 7 polls the 64 flags of this bb-group (lane -> hb)
      if (wave == 7) {
        const unsigned int target = (unsigned int)(t + 1);
        const unsigned int* fp = flags + (size_t)((lane << 2) | bb) * 16;
        while (true) {
          unsigned int v = __hip_atomic_load(fp, __ATOMIC_RELAXED, __HIP_MEMORY_SCOPE_AGENT);
          if (__all((int)(v >= target))) break;
          __builtin_amdgcn_s_sleep(1);
        }
      }
      __syncthreads();  // #3: release all waves into step t+1
    }
  }
}

extern "C" void kernel_launch(void* const* d_in, const int* in_sizes, int n_in,
                              void* d_out, int out_size, void* d_ws, size_t ws_size,
                              hipStream_t stream) {
  const float* x    = (const float*)d_in[0];
  const float* wih  = (const float*)d_in[1];
  const float* whh  = (const float*)d_in[2];
  const float* bias = (const float*)d_in[3];
  float* out = (float*)d_out;

  // ws layout: [flags 16KB][hbuf 2*NB*NH bf16 = 256KB][xbf NB*NS*ND bf16 = 32MB]
  unsigned int*   flags = (unsigned int*)d_ws;
  unsigned short* hbuf  = (unsigned short*)((char*)d_ws + 16384);
  unsigned short* xbf   = (unsigned short*)((char*)d_ws + 16384 + (size_t)2 * NB * NH * 2);

  prep_kernel<<<1024, 256, 0, stream>>>(x, xbf, hbuf, flags);

  void* args[] = { (void*)&wih, (void*)&whh, (void*)&bias,
                   (void*)&xbf, (void*)&hbuf, (void*)&flags, (void*)&out };
  hipLaunchCooperativeKernel((const void*)lstm_kernel, dim3(NWG), dim3(NTHR),
                             args, 0, stream);
}